// Round 4
// baseline (214.375 us; speedup 1.0000x reference)
//
#include <hip/hip_runtime.h>

#define NUM_HEADS 8
#define DIM 64
#define NCLUST 512
#define NTOK 16384          // 8*2048 tokens
#define ROWLEN 512          // NUM_HEADS*DIM floats per token row
#define NIDS (NTOK * NUM_HEADS)           // 131072
#define NMEANS (NUM_HEADS * NCLUST * DIM) // 262144
#define NCK (NUM_HEADS * NCLUST)          // 4096
#define KSPLIT 2
#define KPER (NCLUST / KSPLIT)            // 256 clusters per z-slice

typedef unsigned long long u64;

// ---------------- kernel 0: q[h*K+k] = 0.5*|m_hk|^2 ----------------
__global__ void vq_qnorm(const float* __restrict__ means, float* __restrict__ q) {
    int i = blockIdx.x * blockDim.x + threadIdx.x;   // 0..4095
    const float4* m = (const float4*)(means + (size_t)i * DIM);
    float s = 0.f;
#pragma unroll
    for (int j = 0; j < DIM / 4; ++j) {
        float4 v = m[j];
        s += v.x * v.x + v.y * v.y + v.z * v.z + v.w * v.w;
    }
    q[i] = 0.5f * s;
}

// ---------------- kernel 1: scores + argmin (token-per-thread) ----------------
// Thread = one (token, head); x row (64 f32) in VGPRs. Means rows are read via
// BLOCK-UNIFORM addresses (blockIdx + k loop counter only) -> scalar s_load,
// consumed as the SGPR operand of v_fmac. No LDS, no barriers.
// score(k) = dot(x, m_k) - 0.5*|m_k|^2 ; argmax(score) == argmin(dist).
// Clusters split 2-way over blockIdx.z; packed u64 candidate per slice.
__global__ __launch_bounds__(256) void vq_argmin(const float* __restrict__ x,
                                                 const float* __restrict__ means,
                                                 const float* __restrict__ q,
                                                 u64* __restrict__ cand) {
    const int token = blockIdx.x * 256 + threadIdx.x;
    const int head  = blockIdx.y;
    const int kbase = blockIdx.z * KPER;

    // ---- load this token's x row into registers (16 x dwordx4) ----
    const float4* xrow = (const float4*)(x + (size_t)token * ROWLEN + head * DIM);
    float xr[DIM];
#pragma unroll
    for (int j = 0; j < DIM / 4; ++j) {
        float4 v = xrow[j];
        xr[4 * j + 0] = v.x; xr[4 * j + 1] = v.y;
        xr[4 * j + 2] = v.z; xr[4 * j + 3] = v.w;
    }

    const float* mbase = means + ((size_t)head * NCLUST + kbase) * DIM;
    const float* qbase = q + head * NCLUST + kbase;

    float best = -3.0e38f;
    int bk = kbase;
    for (int k = 0; k < KPER; ++k) {
        const float* m = mbase + (size_t)k * DIM;   // block-uniform -> s_load
        float d0 = 0.f, d1 = 0.f, d2 = 0.f, d3 = 0.f;
#pragma unroll
        for (int j = 0; j < DIM; j += 4) {
            d0 = fmaf(xr[j + 0], m[j + 0], d0);
            d1 = fmaf(xr[j + 1], m[j + 1], d1);
            d2 = fmaf(xr[j + 2], m[j + 2], d2);
            d3 = fmaf(xr[j + 3], m[j + 3], d3);
        }
        float s = (d0 + d1) + (d2 + d3) - qbase[k];
        if (s > best) { best = s; bk = kbase + k; }   // strict > : first-max = smallest k
    }

    // ---- pack (score,k) so u64 MIN == (max score, tie -> min k) ----
    unsigned u = __float_as_uint(best);
    unsigned ord = (u & 0x80000000u) ? ~u : (u | 0x80000000u);  // monotone inc in score
    u64 key = ((u64)(~ord) << 32) | (unsigned)bk;
    cand[(size_t)blockIdx.z * NIDS + (size_t)token * NUM_HEADS + head] = key;
}

// ---------------- kernel 1b: combine the KSPLIT candidates -> float ids ----------------
__global__ void vq_combine(const u64* __restrict__ cand, float* __restrict__ ids_f) {
    int i = blockIdx.x * blockDim.x + threadIdx.x;   // 0..NIDS-1
    u64 a = cand[i];
    u64 b = cand[(size_t)NIDS + i];
    u64 m = (b < a) ? b : a;
    ids_f[i] = (float)(unsigned)(m & 0x1FFu);
}

// ---------------- kernel 2: scatter-accumulate sums & counts ----------------
// One 64-lane wave per (token, head); lane = dim. Replicated accumulators
// (rep = token & (nrep-1)) cut per-address atomic contention.
__global__ void vq_scatter(const float* __restrict__ x,
                           const float* __restrict__ ids_f,
                           float* __restrict__ counts,
                           float* __restrict__ sums,
                           int rep_mask) {
    int gthread = blockIdx.x * blockDim.x + threadIdx.x;
    int w = gthread >> 6;          // pair index, 0..131071
    int lane = threadIdx.x & 63;
    int token = w >> 3;
    int h = w & 7;
    int rep = token & rep_mask;
    int id = (int)ids_f[w];        // broadcast load
    float xv = x[(size_t)token * ROWLEN + h * DIM + lane];
    atomicAdd(&sums[(size_t)rep * NMEANS + (((size_t)h * NCLUST + id) << 6) + lane], xv);
    if (lane == 0) atomicAdd(&counts[rep * NCK + h * NCLUST + id], 1.0f);
}

// ---------------- kernel 3: EMA finalize (sums replicas) ----------------
__global__ void vq_final(const float* __restrict__ means,
                         const float* __restrict__ counts,
                         const float* __restrict__ sums,
                         float* __restrict__ out_means,
                         int nrep) {
    int i = blockIdx.x * blockDim.x + threadIdx.x;   // 0..262143
    int ck = i >> 6;
    float c = 0.f, s = 0.f;
    for (int r = 0; r < nrep; ++r) {
        c += counts[r * NCK + ck];
        s += sums[(size_t)r * NMEANS + i];
    }
    float nm = s / (1e-6f + c);
    out_means[i] = 0.999f * means[i] + 0.001f * nm;
}

extern "C" void kernel_launch(void* const* d_in, const int* in_sizes, int n_in,
                              void* d_out, int out_size, void* d_ws, size_t ws_size,
                              hipStream_t stream) {
    const float* x     = (const float*)d_in[0];   // [8,2048,512]
    const float* means = (const float*)d_in[1];   // [8,512,64]

    float* out       = (float*)d_out;
    float* ids_f     = out;            // 131072 floats (cluster ids as float)
    float* out_means = out + NIDS;     // 262144 floats

    // ---- workspace layout (cand first: 8B alignment) ----
    u64*   cand = (u64*)d_ws;                         // KSPLIT * NIDS u64  (2 MB)
    float* q    = (float*)(cand + (size_t)KSPLIT * NIDS);   // NCK floats
    size_t fixed = (size_t)KSPLIT * NIDS * sizeof(u64) + NCK * sizeof(float);

    // choose scatter replication factor by remaining workspace
    int nrep = 1;
    for (int r = 8; r > 1; r >>= 1) {
        size_t need = fixed + (size_t)r * (NCK + NMEANS) * sizeof(float);
        if (ws_size >= need) { nrep = r; break; }
    }
    float* counts = q + NCK;                      // nrep*NCK
    float* sums   = counts + (size_t)nrep * NCK;  // nrep*NMEANS

    // zero counts + sums every launch (ws is not re-poisoned between replays)
    hipMemsetAsync(counts, 0, (size_t)nrep * (NCK + NMEANS) * sizeof(float), stream);

    vq_qnorm<<<NCK / 256, 256, 0, stream>>>(means, q);

    dim3 g1(NTOK / 256, NUM_HEADS, KSPLIT);
    vq_argmin<<<g1, 256, 0, stream>>>(x, means, q, cand);

    vq_combine<<<NIDS / 256, 256, 0, stream>>>(cand, ids_f);

    vq_scatter<<<(NIDS * 64) / 256, 256, 0, stream>>>(x, ids_f, counts, sums, nrep - 1);

    vq_final<<<NMEANS / 256, 256, 0, stream>>>(means, counts, sums, out_means, nrep);
}